// Round 6
// baseline (1277.477 us; speedup 1.0000x reference)
//
#include <hip/hip_runtime.h>
#include <hip/hip_bf16.h>

// Fused InverseResNet. Round 11: N_wave=64, weights parked in AGPRs via explicit
// scalar accvgpr_write/read asm, ALL MFMAs intrinsic.
// Forensics: R7 and R10 (asm-MFMA consumers) failed with IDENTICAL absmax
// 0.859375 -> deterministic accvgpr_write->asm-MFMA-read hazard (compiler can't
// insert wait states inside asm it can't see). R8/R9 (intrinsic consumers)
// correct but spilled ~130 regs to scratch: VGPR-form ISel makes every
// intrinsic use demand VGPR class -> 404 live > 256 arch file.
// Fix: park each weight scalar via asm "=a" (v_accvgpr_write); unpark at every
// use via VOLATILE asm "a"->"=v" (v_accvgpr_read). The long live range's only
// uses are "a"-constrained -> RA parks it in AGPR (256 free). The VGPR copy
// feeds the INTRINSIC MFMA, so the VALU->MFMA hazard is compiler-visible and
// compiler-managed. volatile on unpark blocks LICM from hoisting reads out of
// the it-loop. 128 accvgpr_reads/phase/wave ~ 128cy, hidden under 2048cy MFMA.
// Structure: 4 waves x N_w=64 x M=64; each ds_read_b128 pair feeds 4 MFMAs ->
// 128KB LDS/phase/CU (<~1000cy) vs 2048cy MFMA/SIMD -> MFMA-bound.

#define B_TOTAL 65536
#define LATENT  128
#define HIDDEN  256
#define OUTD    128
#define NBLOCKS 4
#define NITER   10
#define MTILE   64
#define LDSP    264   // row stride (elems); 528 B rows, 16B-aligned, b128-read conflict-free

typedef unsigned short u16;
typedef unsigned int   u32;
typedef u16    u16x4  __attribute__((ext_vector_type(4)));
typedef u16    u16x8  __attribute__((ext_vector_type(8)));
typedef u32    u32x4  __attribute__((ext_vector_type(4)));
typedef __bf16 bf16x8 __attribute__((ext_vector_type(8)));
typedef float  f32x16 __attribute__((ext_vector_type(16)));

__device__ inline u16 f2b(float f){ __bf16 h=(__bf16)f; return __builtin_bit_cast(u16,h); }
__device__ inline float up_lo(u32 u){ return __builtin_bit_cast(float, u<<16); }
__device__ inline float up_hi(u32 u){ return __builtin_bit_cast(float, u & 0xffff0000u); }
__device__ inline u32 pk2(float lo, float hi){ return (u32)f2b(lo) | ((u32)f2b(hi)<<16); }

#define MFMA_I(a,b,c) __builtin_amdgcn_mfma_f32_32x32x16_bf16(a,b,c,0,0,0)

// Park one u32 in an allocator-assigned AGPR (SSA value of AGPR class).
__device__ inline u32 park(u32 v){
  u32 d;
  asm("v_accvgpr_write_b32 %0, %1" : "=a"(d) : "v"(v));
  return d;
}
// Unpark: AGPR -> fresh VGPR. volatile so LICM can't hoist the reads out of
// the it-loop (which would re-materialize 256 VGPR-resident weights).
__device__ inline u32 unpark(u32 s){
  u32 d;
  asm volatile("v_accvgpr_read_b32 %0, %1" : "=v"(d) : "a"(s));
  return d;
}
__device__ inline bf16x8 unparkq(const u32 p[4]){
  u32x4 t;
  t[0]=unpark(p[0]); t[1]=unpark(p[1]); t[2]=unpark(p[2]); t[3]=unpark(p[3]);
  return __builtin_bit_cast(bf16x8, t);
}

// Weight fragment for the square HIDDENxHIDDEN blocks: 8 k-rows of column col,
// optionally negated (W2 is consumed as -W2 so phase 2 is a pure MFMA-add).
__device__ inline u32x4 wfragq(const float* __restrict__ W, int krow0, int col, bool neg){
  bf16x8 r;
#pragma unroll
  for (int j=0;j<8;j++){
    float v = W[(size_t)(krow0+j)*HIDDEN + col];
    r[j] = (__bf16)(neg ? -v : v);
  }
  return __builtin_bit_cast(u32x4, r);
}

__device__ inline bf16x8 load_wfrag_f(const float* __restrict__ W, int ldw, int krow0,
                                      int col){
  bf16x8 r;
#pragma unroll
  for (int j=0;j<8;j++) r[j] = (__bf16)W[(size_t)(krow0+j)*ldw + col];
  return r;
}

// Store C^T tile to row-major LDS: row = rowbase+lo, cols colbase+8q+4hi+{0..3}.
__device__ inline void store_tile(u16* __restrict__ dst, int row_elem, int colbase, int hi,
                                  const f32x16 a, bool relu){
#pragma unroll
  for (int q=0;q<4;q++){
    u16x4 p;
#pragma unroll
    for (int i=0;i<4;i++){
      float v = a[4*q+i];
      if (relu) v = v > 0.f ? v : 0.f;
      p[i] = f2b(v);
    }
    *(u16x4*)(dst + row_elem + colbase + 8*q + 4*hi) = p;
  }
}

__global__
__attribute__((amdgpu_flat_work_group_size(256,256), amdgpu_waves_per_eu(1,1)))
void irn_kernel(const float* __restrict__ x,
                const float* __restrict__ Winit, const float* __restrict__ binit,
                const float* __restrict__ Wg1,   const float* __restrict__ bg1,
                const float* __restrict__ Wg2,   const float* __restrict__ bg2,
                const float* __restrict__ Wfin,  const float* __restrict__ bfin,
                float* __restrict__ out)
{
  __shared__ u16 Xb[MTILE*LDSP];
  __shared__ u16 Hb[MTILE*LDSP];

  const int tid = threadIdx.x;
  const int wv  = tid >> 6;      // wave 0..3 -> 64-col slice of HIDDEN
  const int ln  = tid & 63;
  const int lo  = ln & 31;
  const int hi  = ln >> 5;
  const int row0 = blockIdx.x * MTILE;
  const int nb   = wv * 64;      // N-slice base (2 x 32-col halves)
  const int colw0 = nb + lo;       // weight col, N-half 0
  const int colw1 = nb + 32 + lo;  // weight col, N-half 1

  // ---- stage x tile [64 x 128] fp32 -> bf16 into Xb (256 threads) ----
  {
    const int r  = tid >> 2;          // 0..63
    const int c0 = (tid & 3) * 32;    // 0,32,64,96
    const float4* src = (const float4*)(x + (size_t)(row0 + r)*LATENT + c0);
    u16* dst = Xb + r*LDSP + c0;
#pragma unroll
    for (int i=0;i<4;i++){
      float4 a = src[i*2], b = src[i*2+1];
      u16x8 p;
      p[0]=f2b(a.x); p[1]=f2b(a.y); p[2]=f2b(a.z); p[3]=f2b(a.w);
      p[4]=f2b(b.x); p[5]=f2b(b.y); p[6]=f2b(b.z); p[7]=f2b(b.w);
      *(u16x8*)(dst + i*8) = p;
    }
  }

  const int rdA0 = lo*LDSP + hi*8;        // activation rows lo / 32+lo
  const int rdA1 = (32+lo)*LDSP + hi*8;

  u32 yp00[8], yp10[8], yp01[8], yp11[8]; // packed bf16x2 y (later y-b2), per tile
  u32 b1p0[8], b1p1[8];                   // packed b1, per N-half

  __syncthreads();

  // ---- initial GEMM: h^T = Winit^T @ x^T (K=128) ----
  {
    bf16x8 wf0[8], wf1[8];
#pragma unroll
    for (int ks=0; ks<8; ks++){
      wf0[ks] = load_wfrag_f(Winit, HIDDEN, ks*16 + hi*8, colw0);
      wf1[ks] = load_wfrag_f(Winit, HIDDEN, ks*16 + hi*8, colw1);
    }
    f32x16 acc00, acc10, acc01, acc11;
#pragma unroll
    for (int r=0;r<16;r++){
      const int cm = (r&3) + 8*(r>>2) + 4*hi;
      float bv0 = binit[nb + cm];
      float bv1 = binit[nb + 32 + cm];
      acc00[r]=bv0; acc10[r]=bv0;
      acc01[r]=bv1; acc11[r]=bv1;
    }
#pragma unroll
    for (int ks=0; ks<8; ks++){
      bf16x8 b0 = *(const bf16x8*)(Xb + rdA0 + ks*16);
      bf16x8 b1 = *(const bf16x8*)(Xb + rdA1 + ks*16);
      acc00=MFMA_I(wf0[ks], b0, acc00);
      acc10=MFMA_I(wf0[ks], b1, acc10);
      acc01=MFMA_I(wf1[ks], b0, acc01);
      acc11=MFMA_I(wf1[ks], b1, acc11);
    }
    __syncthreads();
    store_tile(Xb, (0 +lo)*LDSP, nb,    hi, acc00, false);
    store_tile(Xb, (32+lo)*LDSP, nb,    hi, acc10, false);
    store_tile(Xb, (0 +lo)*LDSP, nb+32, hi, acc01, false);
    store_tile(Xb, (32+lo)*LDSP, nb+32, hi, acc11, false);
#pragma unroll
    for (int i=0;i<8;i++){
      yp00[i] = pk2(acc00[2*i], acc00[2*i+1]);
      yp10[i] = pk2(acc10[2*i], acc10[2*i+1]);
      yp01[i] = pk2(acc01[2*i], acc01[2*i+1]);
      yp11[i] = pk2(acc11[2*i], acc11[2*i+1]);
    }
    __syncthreads();
  }

  // ---- 4 blocks x 10 fixed-point iterations ----
#pragma unroll 1
  for (int b=0; b<NBLOCKS; b++){
    const float* W1p = Wg1 + (size_t)b*HIDDEN*HIDDEN;
    const float* W2p = Wg2 + (size_t)b*HIDDEN*HIDDEN;

    // Park weight fragments in AGPRs: W1 (2 col-halves), -W2 (2 col-halves).
    // 64 frags x 4 scalars = 256 AGPRs; all array indices static after unroll.
    u32 pA[16][4], pB[16][4], pC[16][4], pD[16][4];
#pragma unroll
    for (int ks=0; ks<16; ks++){
      const int kr = ks*16 + hi*8;
      u32x4 a = wfragq(W1p, kr, colw0, false);
      u32x4 c = wfragq(W1p, kr, colw1, false);
      u32x4 d = wfragq(W2p, kr, colw0, true);
      u32x4 e = wfragq(W2p, kr, colw1, true);
#pragma unroll
      for (int i=0;i<4;i++){
        pA[ks][i]=park(a[i]); pB[ks][i]=park(c[i]);
        pC[ks][i]=park(d[i]); pD[ks][i]=park(e[i]);
      }
    }

    { // biases: pack b1; fold b2 into packed y (y <- y - b2)
      const float* b1g = bg1 + b*HIDDEN;
      const float* b2g = bg2 + b*HIDDEN;
#pragma unroll
      for (int i=0;i<8;i++){
        const int cm = (2*i&3) + 8*(2*i>>2) + 4*hi;
        const int c0 = nb + cm, c1 = nb + 32 + cm;
        b1p0[i] = pk2(b1g[c0], b1g[c0+1]);
        b1p1[i] = pk2(b1g[c1], b1g[c1+1]);
        yp00[i] = pk2(up_lo(yp00[i]) - b2g[c0], up_hi(yp00[i]) - b2g[c0+1]);
        yp10[i] = pk2(up_lo(yp10[i]) - b2g[c0], up_hi(yp10[i]) - b2g[c0+1]);
        yp01[i] = pk2(up_lo(yp01[i]) - b2g[c1], up_hi(yp01[i]) - b2g[c1+1]);
        yp11[i] = pk2(up_lo(yp11[i]) - b2g[c1], up_hi(yp11[i]) - b2g[c1+1]);
      }
    }

#pragma unroll 1
    for (int it=0; it<NITER; it++){
      { // phase 1: H = relu(X @ W1 + b1)
        f32x16 acc00, acc10, acc01, acc11;
#pragma unroll
        for (int i=0;i<8;i++){
          acc00[2*i]=up_lo(b1p0[i]); acc00[2*i+1]=up_hi(b1p0[i]);
          acc10[2*i]=acc00[2*i];     acc10[2*i+1]=acc00[2*i+1];
          acc01[2*i]=up_lo(b1p1[i]); acc01[2*i+1]=up_hi(b1p1[i]);
          acc11[2*i]=acc01[2*i];     acc11[2*i+1]=acc01[2*i+1];
        }
#pragma unroll
        for (int ks=0; ks<16; ks++){
          bf16x8 b0 = *(const bf16x8*)(Xb + rdA0 + ks*16);
          bf16x8 b1 = *(const bf16x8*)(Xb + rdA1 + ks*16);
          bf16x8 wa = unparkq(pA[ks]);
          acc00 = MFMA_I(wa, b0, acc00);
          acc10 = MFMA_I(wa, b1, acc10);
          bf16x8 wb = unparkq(pB[ks]);
          acc01 = MFMA_I(wb, b0, acc01);
          acc11 = MFMA_I(wb, b1, acc11);
        }
        store_tile(Hb, (0 +lo)*LDSP, nb,    hi, acc00, true);
        store_tile(Hb, (32+lo)*LDSP, nb,    hi, acc10, true);
        store_tile(Hb, (0 +lo)*LDSP, nb+32, hi, acc01, true);
        store_tile(Hb, (32+lo)*LDSP, nb+32, hi, acc11, true);
      }
      __syncthreads();
      { // phase 2: Xnew = (y - b2) + H @ (-W2)
        f32x16 acc00, acc10, acc01, acc11;
#pragma unroll
        for (int i=0;i<8;i++){
          acc00[2*i]=up_lo(yp00[i]); acc00[2*i+1]=up_hi(yp00[i]);
          acc10[2*i]=up_lo(yp10[i]); acc10[2*i+1]=up_hi(yp10[i]);
          acc01[2*i]=up_lo(yp01[i]); acc01[2*i+1]=up_hi(yp01[i]);
          acc11[2*i]=up_lo(yp11[i]); acc11[2*i+1]=up_hi(yp11[i]);
        }
#pragma unroll
        for (int ks=0; ks<16; ks++){
          bf16x8 b0 = *(const bf16x8*)(Hb + rdA0 + ks*16);
          bf16x8 b1 = *(const bf16x8*)(Hb + rdA1 + ks*16);
          bf16x8 wc = unparkq(pC[ks]);
          acc00 = MFMA_I(wc, b0, acc00);
          acc10 = MFMA_I(wc, b1, acc10);
          bf16x8 wd = unparkq(pD[ks]);
          acc01 = MFMA_I(wd, b0, acc01);
          acc11 = MFMA_I(wd, b1, acc11);
        }
        store_tile(Xb, (0 +lo)*LDSP, nb,    hi, acc00, false);
        store_tile(Xb, (32+lo)*LDSP, nb,    hi, acc10, false);
        store_tile(Xb, (0 +lo)*LDSP, nb+32, hi, acc01, false);
        store_tile(Xb, (32+lo)*LDSP, nb+32, hi, acc11, false);
        if (it == NITER-1){
#pragma unroll
          for (int i=0;i<8;i++){
            yp00[i] = pk2(acc00[2*i], acc00[2*i+1]);
            yp10[i] = pk2(acc10[2*i], acc10[2*i+1]);
            yp01[i] = pk2(acc01[2*i], acc01[2*i+1]);
            yp11[i] = pk2(acc11[2*i], acc11[2*i+1]);
          }
        }
      }
      __syncthreads();
    }
  }

  // ---- final GEMM: out^T = Wfin^T @ X^T ----
  {
    const int mf = wv * 32;         // Wfin col slice (4 waves x 32 = 128)
    bf16x8 wf[16];
#pragma unroll
    for (int ks=0; ks<16; ks++)
      wf[ks] = load_wfrag_f(Wfin, OUTD, ks*16 + hi*8, mf + lo);
    f32x16 acc0, acc1;
#pragma unroll
    for (int r=0;r<16;r++){
      float bv = bfin[mf + (r&3) + 8*(r>>2) + 4*hi];
      acc0[r] = bv; acc1[r] = bv;
    }
#pragma unroll
    for (int ks=0; ks<16; ks++){
      bf16x8 b0 = *(const bf16x8*)(Xb + rdA0 + ks*16);
      bf16x8 b1 = *(const bf16x8*)(Xb + rdA1 + ks*16);
      acc0 = MFMA_I(wf[ks], b0, acc0);
      acc1 = MFMA_I(wf[ks], b1, acc1);
    }
    float* orow0 = out + (size_t)(row0 +      lo)*OUTD;
    float* orow1 = out + (size_t)(row0 + 32 + lo)*OUTD;
#pragma unroll
    for (int q=0;q<4;q++){
      float4 v0 = make_float4(acc0[4*q], acc0[4*q+1], acc0[4*q+2], acc0[4*q+3]);
      float4 v1 = make_float4(acc1[4*q], acc1[4*q+1], acc1[4*q+2], acc1[4*q+3]);
      *(float4*)(orow0 + mf + 8*q + 4*hi) = v0;
      *(float4*)(orow1 + mf + 8*q + 4*hi) = v1;
    }
  }
}

extern "C" void kernel_launch(void* const* d_in, const int* in_sizes, int n_in,
                              void* d_out, int out_size, void* d_ws, size_t ws_size,
                              hipStream_t stream) {
  (void)in_sizes; (void)n_in; (void)d_ws; (void)ws_size; (void)out_size;
  const float* x     = (const float*)d_in[0];
  const float* Winit = (const float*)d_in[1];
  const float* binit = (const float*)d_in[2];
  const float* Wg1   = (const float*)d_in[3];
  const float* bg1   = (const float*)d_in[4];
  const float* Wg2   = (const float*)d_in[5];
  const float* bg2   = (const float*)d_in[6];
  const float* Wfin  = (const float*)d_in[7];
  const float* bfin  = (const float*)d_in[8];
  float* out = (float*)d_out;
  irn_kernel<<<dim3(B_TOTAL/MTILE), dim3(256), 0, stream>>>(
      x, Winit, binit, Wg1, bg1, Wg2, bg2, Wfin, bfin, out);
}

// Round 7
// 793.699 us; speedup vs baseline: 1.6095x; 1.6095x over previous
//
#include <hip/hip_runtime.h>
#include <hip/hip_bf16.h>

// Fused InverseResNet. Round 12: re-anchor on the verified 770us 8-wave R6
// structure (N_wave=64 campaign closed: R7-R11 = 2x miscompile (asm-MFMA
// accvgpr hazard), 3x spill (RA refuses 256 long-lived AGPR weights) -> the
// 4-wave/256-AGPR config is unreachable at HIP source level on this compiler).
// Changes vs R6 (both local, no sync/decomposition change):
//  1. store_tile packs bf16 pairs via pk2 -> guarantees v_cvt_pk_bf16_f32
//     fusion (VALUBusy=25% suspect: scalar casts in u16x4 build not fusing).
//  2. s_setprio(1) around each phase's MFMA cluster (T5): keeps the
//     MFMA-issuing wave prioritized while the co-resident wave issues ds_reads.
// Weights pinned in AGPRs via R6-proven clobber scheme (sound at this LOW arch
// pressure: ~90 live arch regs, no spill -> RA never touches a0-a127).

#define B_TOTAL 65536
#define LATENT  128
#define HIDDEN  256
#define OUTD    128
#define NBLOCKS 4
#define NITER   10
#define MTILE   64
#define LDSP    264   // row stride (elems); 528 B rows, 16B-aligned, b128-read 2-way min

typedef unsigned short u16;
typedef unsigned int   u32;
typedef u16    u16x4  __attribute__((ext_vector_type(4)));
typedef u16    u16x8  __attribute__((ext_vector_type(8)));
typedef u32    u32x2  __attribute__((ext_vector_type(2)));
typedef __bf16 bf16x8 __attribute__((ext_vector_type(8)));
typedef float  f32x16 __attribute__((ext_vector_type(16)));

__device__ inline u16 f2b(float f){ __bf16 h=(__bf16)f; return __builtin_bit_cast(u16,h); }
__device__ inline float up_lo(u32 u){ return __builtin_bit_cast(float, u<<16); }
__device__ inline float up_hi(u32 u){ return __builtin_bit_cast(float, u & 0xffff0000u); }
__device__ inline u32 pk2(float lo, float hi){ return (u32)f2b(lo) | ((u32)f2b(hi)<<16); }

// All 128 weight AGPRs, clobbered on every asm touching them.
#define AGC \
 "a0","a1","a2","a3","a4","a5","a6","a7","a8","a9","a10","a11","a12","a13","a14","a15", \
 "a16","a17","a18","a19","a20","a21","a22","a23","a24","a25","a26","a27","a28","a29","a30","a31", \
 "a32","a33","a34","a35","a36","a37","a38","a39","a40","a41","a42","a43","a44","a45","a46","a47", \
 "a48","a49","a50","a51","a52","a53","a54","a55","a56","a57","a58","a59","a60","a61","a62","a63", \
 "a64","a65","a66","a67","a68","a69","a70","a71","a72","a73","a74","a75","a76","a77","a78","a79", \
 "a80","a81","a82","a83","a84","a85","a86","a87","a88","a89","a90","a91","a92","a93","a94","a95", \
 "a96","a97","a98","a99","a100","a101","a102","a103","a104","a105","a106","a107","a108","a109","a110","a111", \
 "a112","a113","a114","a115","a116","a117","a118","a119","a120","a121","a122","a123","a124","a125","a126","a127"

// Load one K-step weight fragment (8 rows of col colw) into 4 literal AGPRs.
#define LOADW(P, KS, NEG, A0,A1,A2,A3) { \
  const float* _w = (P) + (size_t)((KS)*16 + hi*8)*HIDDEN + colw; \
  float _v0=_w[0], _v1=_w[HIDDEN], _v2=_w[2*HIDDEN], _v3=_w[3*HIDDEN]; \
  float _v4=_w[4*HIDDEN], _v5=_w[5*HIDDEN], _v6=_w[6*HIDDEN], _v7=_w[7*HIDDEN]; \
  if (NEG){_v0=-_v0;_v1=-_v1;_v2=-_v2;_v3=-_v3;_v4=-_v4;_v5=-_v5;_v6=-_v6;_v7=-_v7;} \
  u32 _d0=pk2(_v0,_v1), _d1=pk2(_v2,_v3), _d2=pk2(_v4,_v5), _d3=pk2(_v6,_v7); \
  asm volatile("v_accvgpr_write_b32 a" #A0 ", %0\n\t" \
               "v_accvgpr_write_b32 a" #A1 ", %1\n\t" \
               "v_accvgpr_write_b32 a" #A2 ", %2\n\t" \
               "v_accvgpr_write_b32 a" #A3 ", %3" \
               :: "v"(_d0),"v"(_d1),"v"(_d2),"v"(_d3) : AGC); }

// Issue the 2 LDS b128 reads (rows lo, 32+lo) for K-step KS into a frag pair.
#define LOADP(SRC, KS, FA, FB) { \
  FA = *(const bf16x8*)((SRC) + rdA0 + (KS)*16); \
  FB = *(const bf16x8*)((SRC) + rdA1 + (KS)*16); }

// 2 MFMAs consuming a frag pair against AGPR weights a[A0:A3].
#define MFMA2(FA, FB, A0, A3) { \
  asm volatile("v_mfma_f32_32x32x16_bf16 %0, a[" #A0 ":" #A3 "], %1, %0" \
               : "+v"(acc0) : "v"(FA) : AGC); \
  asm volatile("v_mfma_f32_32x32x16_bf16 %0, a[" #A0 ":" #A3 "], %1, %0" \
               : "+v"(acc1) : "v"(FB) : AGC); }

// MFMA -> VALU-read hazard fence; acc as +v operands pins ordering.
#define ACCFENCE asm volatile("s_nop 7\n\ts_nop 7\n\ts_nop 7" : "+v"(acc0), "+v"(acc1))

// Intrinsic MFMA (used only in init/final GEMMs, outside the AGPR region).
#define MFMA_I(a,b,c) __builtin_amdgcn_mfma_f32_32x32x16_bf16(a,b,c,0,0,0)

__device__ inline bf16x8 load_wfrag_f(const float* __restrict__ W, int ldw, int krow0,
                                      int col){
  bf16x8 r;
#pragma unroll
  for (int j=0;j<8;j++) r[j] = (__bf16)W[(size_t)(krow0+j)*ldw + col];
  return r;
}

// Store C^T tile to row-major LDS: row = rowbase+lo, cols nb+8q+4hi+{0..3}.
// pk2-packed: forces v_cvt_pk_bf16_f32 pairing (identical rounding to scalar).
__device__ inline void store_tile(u16* __restrict__ dst, int row_elem, int nb, int hi,
                                  const f32x16 a, bool relu){
#pragma unroll
  for (int q=0;q<4;q++){
    float v0=a[4*q+0], v1=a[4*q+1], v2=a[4*q+2], v3=a[4*q+3];
    if (relu){
      v0 = v0 > 0.f ? v0 : 0.f;  v1 = v1 > 0.f ? v1 : 0.f;
      v2 = v2 > 0.f ? v2 : 0.f;  v3 = v3 > 0.f ? v3 : 0.f;
    }
    u32x2 p; p[0] = pk2(v0, v1); p[1] = pk2(v2, v3);
    *(u32x2*)(dst + row_elem + nb + 8*q + 4*hi) = p;
  }
}

__global__
__attribute__((amdgpu_flat_work_group_size(512,512)))
void irn_kernel(const float* __restrict__ x,
                const float* __restrict__ Winit, const float* __restrict__ binit,
                const float* __restrict__ Wg1,   const float* __restrict__ bg1,
                const float* __restrict__ Wg2,   const float* __restrict__ bg2,
                const float* __restrict__ Wfin,  const float* __restrict__ bfin,
                float* __restrict__ out)
{
  __shared__ u16 Xb[MTILE*LDSP];
  __shared__ u16 Hb[MTILE*LDSP];

  const int tid = threadIdx.x;
  const int wv  = tid >> 6;      // wave 0..7 -> 32-col slice of HIDDEN
  const int ln  = tid & 63;
  const int lo  = ln & 31;
  const int hi  = ln >> 5;
  const int row0 = blockIdx.x * MTILE;
  const int nb   = wv * 32;
  const int colw = nb + lo;      // this lane's weight column

  // ---- stage x tile [64 x 128] fp32 -> bf16 into Xb ----
  {
    const int r  = tid >> 3;
    const int c0 = (tid & 7) * 16;
    const float4* src = (const float4*)(x + (size_t)(row0 + r)*LATENT + c0);
    u16x8 p0, p1;
#pragma unroll
    for (int i=0;i<2;i++){
      float4 a = src[i*2], b = src[i*2+1];
      u16x8& p = i ? p1 : p0;
      p[0]=f2b(a.x); p[1]=f2b(a.y); p[2]=f2b(a.z); p[3]=f2b(a.w);
      p[4]=f2b(b.x); p[5]=f2b(b.y); p[6]=f2b(b.z); p[7]=f2b(b.w);
    }
    u16* dst = Xb + r*LDSP + c0;
    *(u16x8*)(dst)   = p0;
    *(u16x8*)(dst+8) = p1;
  }

  const int rdA0 = lo*LDSP + hi*8;        // activation rows lo / 32+lo
  const int rdA1 = (32+lo)*LDSP + hi*8;

  u32 yp0[8], yp1[8];   // packed bf16x2 y (later y-b2), C^T reg order
  u32 b1p[8];           // packed b1

  __syncthreads();

  // ---- initial GEMM: h^T = Winit^T @ x^T (K=128), intrinsics (pre-AGPR region) ----
  {
    bf16x8 wf[8];
#pragma unroll
    for (int ks=0; ks<8; ks++)
      wf[ks] = load_wfrag_f(Winit, HIDDEN, ks*16 + hi*8, colw);
    f32x16 acc0, acc1;
#pragma unroll
    for (int r=0;r<16;r++){
      float bv = binit[nb + (r&3) + 8*(r>>2) + 4*hi];
      acc0[r]=bv; acc1[r]=bv;
    }
#pragma unroll
    for (int ks=0; ks<8; ks++){
      bf16x8 b0 = *(const bf16x8*)(Xb + rdA0 + ks*16);
      bf16x8 b1 = *(const bf16x8*)(Xb + rdA1 + ks*16);
      acc0=MFMA_I(wf[ks], b0, acc0);
      acc1=MFMA_I(wf[ks], b1, acc1);
    }
    __syncthreads();
    store_tile(Xb, (0 +lo)*LDSP, nb, hi, acc0, false);
    store_tile(Xb, (32+lo)*LDSP, nb, hi, acc1, false);
#pragma unroll
    for (int i=0;i<8;i++){
      yp0[i] = pk2(acc0[2*i], acc0[2*i+1]);
      yp1[i] = pk2(acc1[2*i], acc1[2*i+1]);
    }
    __syncthreads();
  }

  // ---- 4 blocks x 10 fixed-point iterations ----
#pragma unroll 1
  for (int b=0; b<NBLOCKS; b++){
    const float* W1p = Wg1 + (size_t)b*HIDDEN*HIDDEN;
    const float* W2p = Wg2 + (size_t)b*HIDDEN*HIDDEN;

    // W1 -> a0..a63
    LOADW(W1p, 0,0,  0,1,2,3)    LOADW(W1p, 1,0,  4,5,6,7)
    LOADW(W1p, 2,0,  8,9,10,11)  LOADW(W1p, 3,0,  12,13,14,15)
    LOADW(W1p, 4,0,  16,17,18,19) LOADW(W1p, 5,0,  20,21,22,23)
    LOADW(W1p, 6,0,  24,25,26,27) LOADW(W1p, 7,0,  28,29,30,31)
    LOADW(W1p, 8,0,  32,33,34,35) LOADW(W1p, 9,0,  36,37,38,39)
    LOADW(W1p,10,0,  40,41,42,43) LOADW(W1p,11,0,  44,45,46,47)
    LOADW(W1p,12,0,  48,49,50,51) LOADW(W1p,13,0,  52,53,54,55)
    LOADW(W1p,14,0,  56,57,58,59) LOADW(W1p,15,0,  60,61,62,63)
    // -W2 -> a64..a127
    LOADW(W2p, 0,1,  64,65,66,67)   LOADW(W2p, 1,1,  68,69,70,71)
    LOADW(W2p, 2,1,  72,73,74,75)   LOADW(W2p, 3,1,  76,77,78,79)
    LOADW(W2p, 4,1,  80,81,82,83)   LOADW(W2p, 5,1,  84,85,86,87)
    LOADW(W2p, 6,1,  88,89,90,91)   LOADW(W2p, 7,1,  92,93,94,95)
    LOADW(W2p, 8,1,  96,97,98,99)   LOADW(W2p, 9,1,  100,101,102,103)
    LOADW(W2p,10,1,  104,105,106,107) LOADW(W2p,11,1,  108,109,110,111)
    LOADW(W2p,12,1,  112,113,114,115) LOADW(W2p,13,1,  116,117,118,119)
    LOADW(W2p,14,1,  120,121,122,123) LOADW(W2p,15,1,  124,125,126,127)
    asm volatile("s_nop 3" :::);   // accvgpr_write -> MFMA-read wait states

    { // biases: pack b1; fold b2 into packed y (y <- y - b2), both exact-bf16 stores
      const float* b1g = bg1 + b*HIDDEN;
      const float* b2g = bg2 + b*HIDDEN;
#pragma unroll
      for (int i=0;i<8;i++){
        const int c = nb + (2*i&3) + 8*(2*i>>2) + 4*hi;
        b1p[i] = pk2(b1g[c], b1g[c+1]);
        yp0[i] = pk2(up_lo(yp0[i]) - b2g[c], up_hi(yp0[i]) - b2g[c+1]);
        yp1[i] = pk2(up_lo(yp1[i]) - b2g[c], up_hi(yp1[i]) - b2g[c+1]);
      }
    }

#pragma unroll 1
    for (int it=0; it<NITER; it++){
      { // phase 1: H = relu(X @ W1 + b1) -- depth-4 pipelined reads
        bf16x8 f0a,f0b,f1a,f1b,f2a,f2b,f3a,f3b;
        LOADP(Xb,0,f0a,f0b) LOADP(Xb,1,f1a,f1b)
        LOADP(Xb,2,f2a,f2b) LOADP(Xb,3,f3a,f3b)
        f32x16 acc0, acc1;   // init VALU hides under first-load latency
#pragma unroll
        for (int i=0;i<8;i++){
          acc0[2*i]=up_lo(b1p[i]); acc0[2*i+1]=up_hi(b1p[i]);
          acc1[2*i]=acc0[2*i];     acc1[2*i+1]=acc0[2*i+1];
        }
        __builtin_amdgcn_s_setprio(1);
        MFMA2(f0a,f0b, 0, 3)  LOADP(Xb, 4,f0a,f0b)
        MFMA2(f1a,f1b, 4, 7)  LOADP(Xb, 5,f1a,f1b)
        MFMA2(f2a,f2b, 8,11)  LOADP(Xb, 6,f2a,f2b)
        MFMA2(f3a,f3b,12,15)  LOADP(Xb, 7,f3a,f3b)
        MFMA2(f0a,f0b,16,19)  LOADP(Xb, 8,f0a,f0b)
        MFMA2(f1a,f1b,20,23)  LOADP(Xb, 9,f1a,f1b)
        MFMA2(f2a,f2b,24,27)  LOADP(Xb,10,f2a,f2b)
        MFMA2(f3a,f3b,28,31)  LOADP(Xb,11,f3a,f3b)
        MFMA2(f0a,f0b,32,35)  LOADP(Xb,12,f0a,f0b)
        MFMA2(f1a,f1b,36,39)  LOADP(Xb,13,f1a,f1b)
        MFMA2(f2a,f2b,40,43)  LOADP(Xb,14,f2a,f2b)
        MFMA2(f3a,f3b,44,47)  LOADP(Xb,15,f3a,f3b)
        MFMA2(f0a,f0b,48,51)
        MFMA2(f1a,f1b,52,55)
        MFMA2(f2a,f2b,56,59)
        MFMA2(f3a,f3b,60,63)
        __builtin_amdgcn_s_setprio(0);
        ACCFENCE;
        store_tile(Hb, (0 +lo)*LDSP, nb, hi, acc0, true);
        store_tile(Hb, (32+lo)*LDSP, nb, hi, acc1, true);
      }
      __syncthreads();
      { // phase 2: Xnew = (y - b2) + H @ (-W2) -- depth-4 pipelined reads
        bf16x8 f0a,f0b,f1a,f1b,f2a,f2b,f3a,f3b;
        LOADP(Hb,0,f0a,f0b) LOADP(Hb,1,f1a,f1b)
        LOADP(Hb,2,f2a,f2b) LOADP(Hb,3,f3a,f3b)
        f32x16 acc0, acc1;
#pragma unroll
        for (int i=0;i<8;i++){
          acc0[2*i]=up_lo(yp0[i]); acc0[2*i+1]=up_hi(yp0[i]);
          acc1[2*i]=up_lo(yp1[i]); acc1[2*i+1]=up_hi(yp1[i]);
        }
        __builtin_amdgcn_s_setprio(1);
        MFMA2(f0a,f0b, 64, 67)  LOADP(Hb, 4,f0a,f0b)
        MFMA2(f1a,f1b, 68, 71)  LOADP(Hb, 5,f1a,f1b)
        MFMA2(f2a,f2b, 72, 75)  LOADP(Hb, 6,f2a,f2b)
        MFMA2(f3a,f3b, 76, 79)  LOADP(Hb, 7,f3a,f3b)
        MFMA2(f0a,f0b, 80, 83)  LOADP(Hb, 8,f0a,f0b)
        MFMA2(f1a,f1b, 84, 87)  LOADP(Hb, 9,f1a,f1b)
        MFMA2(f2a,f2b, 88, 91)  LOADP(Hb,10,f2a,f2b)
        MFMA2(f3a,f3b, 92, 95)  LOADP(Hb,11,f3a,f3b)
        MFMA2(f0a,f0b, 96, 99)  LOADP(Hb,12,f0a,f0b)
        MFMA2(f1a,f1b,100,103)  LOADP(Hb,13,f1a,f1b)
        MFMA2(f2a,f2b,104,107)  LOADP(Hb,14,f2a,f2b)
        MFMA2(f3a,f3b,108,111)  LOADP(Hb,15,f3a,f3b)
        MFMA2(f0a,f0b,112,115)
        MFMA2(f1a,f1b,116,119)
        MFMA2(f2a,f2b,120,123)
        MFMA2(f3a,f3b,124,127)
        __builtin_amdgcn_s_setprio(0);
        ACCFENCE;
        store_tile(Xb, (0 +lo)*LDSP, nb, hi, acc0, false);
        store_tile(Xb, (32+lo)*LDSP, nb, hi, acc1, false);
        if (it == NITER-1){
#pragma unroll
          for (int i=0;i<8;i++){
            yp0[i] = pk2(acc0[2*i], acc0[2*i+1]);
            yp1[i] = pk2(acc1[2*i], acc1[2*i+1]);
          }
        }
      }
      __syncthreads();
    }
  }

  // ---- final GEMM: out^T = Wfin^T @ X^T (intrinsics, post-AGPR region) ----
  {
    const int mf = (wv & 3) * 32;   // Wfin col slice
    const int nf = (wv >> 2);       // row half
    const int rdF = (nf*32 + lo)*LDSP + hi*8;
    bf16x8 wf[16];
#pragma unroll
    for (int ks=0; ks<16; ks++)
      wf[ks] = load_wfrag_f(Wfin, OUTD, ks*16 + hi*8, mf + lo);
    f32x16 acc;
#pragma unroll
    for (int r=0;r<16;r++) acc[r] = bfin[mf + (r&3) + 8*(r>>2) + 4*hi];
#pragma unroll
    for (int ks=0; ks<16; ks++){
      bf16x8 bfr = *(const bf16x8*)(Xb + rdF + ks*16);
      acc = MFMA_I(wf[ks], bfr, acc);
    }
    float* orow = out + (size_t)(row0 + nf*32 + lo)*OUTD;
#pragma unroll
    for (int q=0;q<4;q++){
      float4 v = make_float4(acc[4*q], acc[4*q+1], acc[4*q+2], acc[4*q+3]);
      *(float4*)(orow + mf + 8*q + 4*hi) = v;
    }
  }
}

extern "C" void kernel_launch(void* const* d_in, const int* in_sizes, int n_in,
                              void* d_out, int out_size, void* d_ws, size_t ws_size,
                              hipStream_t stream) {
  (void)in_sizes; (void)n_in; (void)d_ws; (void)ws_size; (void)out_size;
  const float* x     = (const float*)d_in[0];
  const float* Winit = (const float*)d_in[1];
  const float* binit = (const float*)d_in[2];
  const float* Wg1   = (const float*)d_in[3];
  const float* bg1   = (const float*)d_in[4];
  const float* Wg2   = (const float*)d_in[5];
  const float* bg2   = (const float*)d_in[6];
  const float* Wfin  = (const float*)d_in[7];
  const float* bfin  = (const float*)d_in[8];
  float* out = (float*)d_out;
  irn_kernel<<<dim3(B_TOTAL/MTILE), dim3(512), 0, stream>>>(
      x, Winit, binit, Wg1, bg1, Wg2, bg2, Wfin, bfin, out);
}

// Round 8
// 774.174 us; speedup vs baseline: 1.6501x; 1.0252x over previous
//
#include <hip/hip_runtime.h>
#include <hip/hip_bf16.h>

// Fused InverseResNet. Round 13: revert R12's regressions (pk2 epilogue,
// setprio: VALUBusy 25->31, dur +25us) back to the verified 768us round-0
// structure, plus ONE counter-targeted change: k-permutation sigma on the
// hidden-dim LDS layout to kill the write-side bank conflicts.
// Evidence: SQ_LDS_BANK_CONFLICT = 2.136e7 invariant across ALL rounds (even
// 4-wave variants with half the reads) -> it's the epilogue b64 writes: cols
// nb+8q+4hi are 16B-grid-even, row stride 132 dwords = 4 mod 32 -> 128 write
// dwords on 16 of 32 banks = 2x serialization (~512 cy/phase on the LDS pipe).
// Fix: store lane's acc[r] at L-col = nb + 16hi + r (contiguous 32B -> 2x b128
// writes, full 32-bank coverage, 8 dwords/bank = minimum). Consistency moves to
// the weight loaders: A-frag k-rows for L-col run (ks,hi) are
//   n = 32*(ks>>1) + 4*(ks&1) + 16*hi + {0,1,2,3,8,9,10,11}
// applied to W1, W2 (LOADW) and Wfin (final GEMM). Init staging (latent,
// identity), Winit rows, biases, yp packing, out store: value-space, unchanged.
// Weights pinned in AGPRs via the R6-proven clobber scheme (sound at this low
// arch pressure: ~90 live arch regs, RA never spills into a0-a127).

#define B_TOTAL 65536
#define LATENT  128
#define HIDDEN  256
#define OUTD    128
#define NBLOCKS 4
#define NITER   10
#define MTILE   64
#define LDSP    264   // row stride (elems); 528 B rows, 16B-aligned

typedef unsigned short u16;
typedef unsigned int   u32;
typedef u16    u16x4  __attribute__((ext_vector_type(4)));
typedef u16    u16x8  __attribute__((ext_vector_type(8)));
typedef __bf16 bf16x8 __attribute__((ext_vector_type(8)));
typedef float  f32x16 __attribute__((ext_vector_type(16)));

__device__ inline u16 f2b(float f){ __bf16 h=(__bf16)f; return __builtin_bit_cast(u16,h); }
__device__ inline float up_lo(u32 u){ return __builtin_bit_cast(float, u<<16); }
__device__ inline float up_hi(u32 u){ return __builtin_bit_cast(float, u & 0xffff0000u); }
__device__ inline u32 pk2(float lo, float hi){ return (u32)f2b(lo) | ((u32)f2b(hi)<<16); }

// All 128 weight AGPRs, clobbered on every asm touching them.
#define AGC \
 "a0","a1","a2","a3","a4","a5","a6","a7","a8","a9","a10","a11","a12","a13","a14","a15", \
 "a16","a17","a18","a19","a20","a21","a22","a23","a24","a25","a26","a27","a28","a29","a30","a31", \
 "a32","a33","a34","a35","a36","a37","a38","a39","a40","a41","a42","a43","a44","a45","a46","a47", \
 "a48","a49","a50","a51","a52","a53","a54","a55","a56","a57","a58","a59","a60","a61","a62","a63", \
 "a64","a65","a66","a67","a68","a69","a70","a71","a72","a73","a74","a75","a76","a77","a78","a79", \
 "a80","a81","a82","a83","a84","a85","a86","a87","a88","a89","a90","a91","a92","a93","a94","a95", \
 "a96","a97","a98","a99","a100","a101","a102","a103","a104","a105","a106","a107","a108","a109","a110","a111", \
 "a112","a113","a114","a115","a116","a117","a118","a119","a120","a121","a122","a123","a124","a125","a126","a127"

// Load one K-step weight fragment into 4 literal AGPRs, with sigma-permuted
// k-rows matching the LDS L-layout: rows _kb + {0,1,2,3,8,9,10,11}.
#define LOADW(P, KS, NEG, A0,A1,A2,A3) { \
  const int _kb = ((KS)>>1)*32 + ((KS)&1)*4 + hi*16; \
  const float* _w = (P) + (size_t)_kb*HIDDEN + colw; \
  float _v0=_w[0],          _v1=_w[HIDDEN],    _v2=_w[2*HIDDEN],  _v3=_w[3*HIDDEN]; \
  float _v4=_w[8*HIDDEN],   _v5=_w[9*HIDDEN],  _v6=_w[10*HIDDEN], _v7=_w[11*HIDDEN]; \
  if (NEG){_v0=-_v0;_v1=-_v1;_v2=-_v2;_v3=-_v3;_v4=-_v4;_v5=-_v5;_v6=-_v6;_v7=-_v7;} \
  u32 _d0=pk2(_v0,_v1), _d1=pk2(_v2,_v3), _d2=pk2(_v4,_v5), _d3=pk2(_v6,_v7); \
  asm volatile("v_accvgpr_write_b32 a" #A0 ", %0\n\t" \
               "v_accvgpr_write_b32 a" #A1 ", %1\n\t" \
               "v_accvgpr_write_b32 a" #A2 ", %2\n\t" \
               "v_accvgpr_write_b32 a" #A3 ", %3" \
               :: "v"(_d0),"v"(_d1),"v"(_d2),"v"(_d3) : AGC); }

// One K-step: 2 LDS b128 reads (rows lo, 32+lo) + 2 MFMAs from AGPR weights.
#define STEP(SRC, KS, A0, A3) { \
  bf16x8 _b0 = *(const bf16x8*)((SRC) + rdA0 + (KS)*16); \
  bf16x8 _b1 = *(const bf16x8*)((SRC) + rdA1 + (KS)*16); \
  asm volatile("v_mfma_f32_32x32x16_bf16 %0, a[" #A0 ":" #A3 "], %1, %0" \
               : "+v"(acc0) : "v"(_b0) : AGC); \
  asm volatile("v_mfma_f32_32x32x16_bf16 %0, a[" #A0 ":" #A3 "], %1, %0" \
               : "+v"(acc1) : "v"(_b1) : AGC); }

// MFMA -> VALU-read hazard fence; acc as +v operands pins ordering.
#define ACCFENCE asm volatile("s_nop 7\n\ts_nop 7\n\ts_nop 7" : "+v"(acc0), "+v"(acc1))

// Intrinsic MFMA (used only in init/final GEMMs, outside the AGPR region).
#define MFMA_I(a,b,c) __builtin_amdgcn_mfma_f32_32x32x16_bf16(a,b,c,0,0,0)

// Contiguous-row weight fragment (init GEMM; latent dim is identity-layout).
__device__ inline bf16x8 load_wfrag_f(const float* __restrict__ W, int ldw, int krow0,
                                      int col){
  bf16x8 r;
#pragma unroll
  for (int j=0;j<8;j++) r[j] = (__bf16)W[(size_t)(krow0+j)*ldw + col];
  return r;
}

// Sigma-permuted weight fragment (final GEMM; hidden dim is L-layout):
// rows kb + {0,1,2,3,8,9,10,11}, kb = 32*(ks>>1) + 4*(ks&1) + 16*hi.
__device__ inline bf16x8 load_wfrag_p(const float* __restrict__ W, int ldw, int ks,
                                      int hi, int col){
  const int kb = (ks>>1)*32 + (ks&1)*4 + hi*16;
  bf16x8 r;
#pragma unroll
  for (int j=0;j<8;j++) r[j] = (__bf16)W[(size_t)(kb + (j&3) + 8*(j>>2))*ldw + col];
  return r;
}

// Store C^T tile to sigma-layout LDS: row = rowbase+lo, L-cols nb+16hi+{0..15}.
// Lane's 16 acc values are contiguous -> 2x b128 writes, full 32-bank spread.
__device__ inline void store_tile(u16* __restrict__ dst, int row_elem, int nb, int hi,
                                  const f32x16 a, bool relu){
  u16x8 p0, p1;
#pragma unroll
  for (int i=0;i<8;i++){
    float v0 = a[i], v1 = a[8+i];
    if (relu){ v0 = v0 > 0.f ? v0 : 0.f;  v1 = v1 > 0.f ? v1 : 0.f; }
    p0[i] = f2b(v0);  p1[i] = f2b(v1);
  }
  u16* p = dst + row_elem + nb + 16*hi;
  *(u16x8*)(p)     = p0;
  *(u16x8*)(p + 8) = p1;
}

__global__
__attribute__((amdgpu_flat_work_group_size(512,512)))
void irn_kernel(const float* __restrict__ x,
                const float* __restrict__ Winit, const float* __restrict__ binit,
                const float* __restrict__ Wg1,   const float* __restrict__ bg1,
                const float* __restrict__ Wg2,   const float* __restrict__ bg2,
                const float* __restrict__ Wfin,  const float* __restrict__ bfin,
                float* __restrict__ out)
{
  __shared__ u16 Xb[MTILE*LDSP];
  __shared__ u16 Hb[MTILE*LDSP];

  const int tid = threadIdx.x;
  const int wv  = tid >> 6;      // wave 0..7 -> 32-col slice of HIDDEN
  const int ln  = tid & 63;
  const int lo  = ln & 31;
  const int hi  = ln >> 5;
  const int row0 = blockIdx.x * MTILE;
  const int nb   = wv * 32;
  const int colw = nb + lo;      // this lane's weight column

  // ---- stage x tile [64 x 128] fp32 -> bf16 into Xb (latent: identity) ----
  {
    const int r  = tid >> 3;
    const int c0 = (tid & 7) * 16;
    const float4* src = (const float4*)(x + (size_t)(row0 + r)*LATENT + c0);
    u16x8 p0, p1;
#pragma unroll
    for (int i=0;i<2;i++){
      float4 a = src[i*2], b = src[i*2+1];
      u16x8& p = i ? p1 : p0;
      p[0]=f2b(a.x); p[1]=f2b(a.y); p[2]=f2b(a.z); p[3]=f2b(a.w);
      p[4]=f2b(b.x); p[5]=f2b(b.y); p[6]=f2b(b.z); p[7]=f2b(b.w);
    }
    u16* dst = Xb + r*LDSP + c0;
    *(u16x8*)(dst)   = p0;
    *(u16x8*)(dst+8) = p1;
  }

  const int rdA0 = lo*LDSP + hi*8;        // activation rows lo / 32+lo
  const int rdA1 = (32+lo)*LDSP + hi*8;

  u32 yp0[8], yp1[8];   // packed bf16x2 y (later y-b2), C^T reg order
  u32 b1p[8];           // packed b1

  __syncthreads();

  // ---- initial GEMM: h^T = Winit^T @ x^T (K=128), intrinsics (pre-AGPR region) ----
  {
    bf16x8 wf[8];
#pragma unroll
    for (int ks=0; ks<8; ks++)
      wf[ks] = load_wfrag_f(Winit, HIDDEN, ks*16 + hi*8, colw);
    f32x16 acc0, acc1;
#pragma unroll
    for (int r=0;r<16;r++){
      float bv = binit[nb + (r&3) + 8*(r>>2) + 4*hi];
      acc0[r]=bv; acc1[r]=bv;
    }
#pragma unroll
    for (int ks=0; ks<8; ks++){
      bf16x8 b0 = *(const bf16x8*)(Xb + rdA0 + ks*16);
      bf16x8 b1 = *(const bf16x8*)(Xb + rdA1 + ks*16);
      acc0=MFMA_I(wf[ks], b0, acc0);
      acc1=MFMA_I(wf[ks], b1, acc1);
    }
    __syncthreads();
    store_tile(Xb, (0 +lo)*LDSP, nb, hi, acc0, false);   // sigma-layout from here on
    store_tile(Xb, (32+lo)*LDSP, nb, hi, acc1, false);
#pragma unroll
    for (int i=0;i<8;i++){
      yp0[i] = pk2(acc0[2*i], acc0[2*i+1]);
      yp1[i] = pk2(acc1[2*i], acc1[2*i+1]);
    }
    __syncthreads();
  }

  // ---- 4 blocks x 10 fixed-point iterations ----
#pragma unroll 1
  for (int b=0; b<NBLOCKS; b++){
    const float* W1p = Wg1 + (size_t)b*HIDDEN*HIDDEN;
    const float* W2p = Wg2 + (size_t)b*HIDDEN*HIDDEN;

    // W1 -> a0..a63 (sigma-permuted k-rows)
    LOADW(W1p, 0,0,  0,1,2,3)    LOADW(W1p, 1,0,  4,5,6,7)
    LOADW(W1p, 2,0,  8,9,10,11)  LOADW(W1p, 3,0,  12,13,14,15)
    LOADW(W1p, 4,0,  16,17,18,19) LOADW(W1p, 5,0,  20,21,22,23)
    LOADW(W1p, 6,0,  24,25,26,27) LOADW(W1p, 7,0,  28,29,30,31)
    LOADW(W1p, 8,0,  32,33,34,35) LOADW(W1p, 9,0,  36,37,38,39)
    LOADW(W1p,10,0,  40,41,42,43) LOADW(W1p,11,0,  44,45,46,47)
    LOADW(W1p,12,0,  48,49,50,51) LOADW(W1p,13,0,  52,53,54,55)
    LOADW(W1p,14,0,  56,57,58,59) LOADW(W1p,15,0,  60,61,62,63)
    // -W2 -> a64..a127 (sigma-permuted k-rows)
    LOADW(W2p, 0,1,  64,65,66,67)   LOADW(W2p, 1,1,  68,69,70,71)
    LOADW(W2p, 2,1,  72,73,74,75)   LOADW(W2p, 3,1,  76,77,78,79)
    LOADW(W2p, 4,1,  80,81,82,83)   LOADW(W2p, 5,1,  84,85,86,87)
    LOADW(W2p, 6,1,  88,89,90,91)   LOADW(W2p, 7,1,  92,93,94,95)
    LOADW(W2p, 8,1,  96,97,98,99)   LOADW(W2p, 9,1,  100,101,102,103)
    LOADW(W2p,10,1,  104,105,106,107) LOADW(W2p,11,1,  108,109,110,111)
    LOADW(W2p,12,1,  112,113,114,115) LOADW(W2p,13,1,  116,117,118,119)
    LOADW(W2p,14,1,  120,121,122,123) LOADW(W2p,15,1,  124,125,126,127)
    asm volatile("s_nop 3" :::);   // accvgpr_write -> MFMA-read wait states

    { // biases: pack b1; fold b2 into packed y (y <- y - b2) -- value space
      const float* b1g = bg1 + b*HIDDEN;
      const float* b2g = bg2 + b*HIDDEN;
#pragma unroll
      for (int i=0;i<8;i++){
        const int c = nb + (2*i&3) + 8*(2*i>>2) + 4*hi;
        b1p[i] = pk2(b1g[c], b1g[c+1]);
        yp0[i] = pk2(up_lo(yp0[i]) - b2g[c], up_hi(yp0[i]) - b2g[c+1]);
        yp1[i] = pk2(up_lo(yp1[i]) - b2g[c], up_hi(yp1[i]) - b2g[c+1]);
      }
    }

#pragma unroll 1
    for (int it=0; it<NITER; it++){
      { // phase 1: H = relu(X @ W1 + b1)
        f32x16 acc0, acc1;
#pragma unroll
        for (int i=0;i<8;i++){
          acc0[2*i]=up_lo(b1p[i]); acc0[2*i+1]=up_hi(b1p[i]);
          acc1[2*i]=acc0[2*i];     acc1[2*i+1]=acc0[2*i+1];
        }
        STEP(Xb, 0, 0,3)   STEP(Xb, 1, 4,7)   STEP(Xb, 2, 8,11)  STEP(Xb, 3, 12,15)
        STEP(Xb, 4, 16,19) STEP(Xb, 5, 20,23) STEP(Xb, 6, 24,27) STEP(Xb, 7, 28,31)
        STEP(Xb, 8, 32,35) STEP(Xb, 9, 36,39) STEP(Xb,10, 40,43) STEP(Xb,11, 44,47)
        STEP(Xb,12, 48,51) STEP(Xb,13, 52,55) STEP(Xb,14, 56,59) STEP(Xb,15, 60,63)
        ACCFENCE;
        store_tile(Hb, (0 +lo)*LDSP, nb, hi, acc0, true);
        store_tile(Hb, (32+lo)*LDSP, nb, hi, acc1, true);
      }
      __syncthreads();
      { // phase 2: Xnew = (y - b2) + H @ (-W2)
        f32x16 acc0, acc1;
#pragma unroll
        for (int i=0;i<8;i++){
          acc0[2*i]=up_lo(yp0[i]); acc0[2*i+1]=up_hi(yp0[i]);
          acc1[2*i]=up_lo(yp1[i]); acc1[2*i+1]=up_hi(yp1[i]);
        }
        STEP(Hb, 0, 64,67)   STEP(Hb, 1, 68,71)   STEP(Hb, 2, 72,75)   STEP(Hb, 3, 76,79)
        STEP(Hb, 4, 80,83)   STEP(Hb, 5, 84,87)   STEP(Hb, 6, 88,91)   STEP(Hb, 7, 92,95)
        STEP(Hb, 8, 96,99)   STEP(Hb, 9, 100,103) STEP(Hb,10, 104,107) STEP(Hb,11, 108,111)
        STEP(Hb,12, 112,115) STEP(Hb,13, 116,119) STEP(Hb,14, 120,123) STEP(Hb,15, 124,127)
        ACCFENCE;
        store_tile(Xb, (0 +lo)*LDSP, nb, hi, acc0, false);
        store_tile(Xb, (32+lo)*LDSP, nb, hi, acc1, false);
        if (it == NITER-1){
#pragma unroll
          for (int i=0;i<8;i++){
            yp0[i] = pk2(acc0[2*i], acc0[2*i+1]);
            yp1[i] = pk2(acc1[2*i], acc1[2*i+1]);
          }
        }
      }
      __syncthreads();
    }
  }

  // ---- final GEMM: out^T = Wfin^T @ X^T (sigma-permuted Wfin rows) ----
  {
    const int mf = (wv & 3) * 32;   // Wfin col slice
    const int nf = (wv >> 2);       // row half
    const int rdF = (nf*32 + lo)*LDSP + hi*8;
    bf16x8 wf[16];
#pragma unroll
    for (int ks=0; ks<16; ks++)
      wf[ks] = load_wfrag_p(Wfin, OUTD, ks, hi, mf + lo);
    f32x16 acc;
#pragma unroll
    for (int r=0;r<16;r++) acc[r] = bfin[mf + (r&3) + 8*(r>>2) + 4*hi];
#pragma unroll
    for (int ks=0; ks<16; ks++){
      bf16x8 bfr = *(const bf16x8*)(Xb + rdF + ks*16);
      acc = MFMA_I(wf[ks], bfr, acc);
    }
    float* orow = out + (size_t)(row0 + nf*32 + lo)*OUTD;
#pragma unroll
    for (int q=0;q<4;q++){
      float4 v = make_float4(acc[4*q], acc[4*q+1], acc[4*q+2], acc[4*q+3]);
      *(float4*)(orow + mf + 8*q + 4*hi) = v;
    }
  }
}

extern "C" void kernel_launch(void* const* d_in, const int* in_sizes, int n_in,
                              void* d_out, int out_size, void* d_ws, size_t ws_size,
                              hipStream_t stream) {
  (void)in_sizes; (void)n_in; (void)d_ws; (void)ws_size; (void)out_size;
  const float* x     = (const float*)d_in[0];
  const float* Winit = (const float*)d_in[1];
  const float* binit = (const float*)d_in[2];
  const float* Wg1   = (const float*)d_in[3];
  const float* bg1   = (const float*)d_in[4];
  const float* Wg2   = (const float*)d_in[5];
  const float* bg2   = (const float*)d_in[6];
  const float* Wfin  = (const float*)d_in[7];
  const float* bfin  = (const float*)d_in[8];
  float* out = (float*)d_out;
  irn_kernel<<<dim3(B_TOTAL/MTILE), dim3(512), 0, stream>>>(
      x, Winit, binit, Wg1, bg1, Wg2, bg2, Wfin, bfin, out);
}